// Round 4
// baseline (407.984 us; speedup 1.0000x reference)
//
#include <hip/hip_runtime.h>
#include <cstdint>

typedef __attribute__((ext_vector_type(8))) short bf16x8;
typedef __attribute__((ext_vector_type(4))) float f32x4;

#define DEV static __device__ __forceinline__

DEV unsigned short f2bf(float f) {
  unsigned int u = __builtin_bit_cast(unsigned int, f);
  u += 0x7FFFu + ((u >> 16) & 1u);
  return (unsigned short)(u >> 16);
}
DEV float bf2f(unsigned short h) {
  unsigned int u = ((unsigned int)h) << 16;
  return __builtin_bit_cast(float, u);
}

// ---------------------------------------------------------------------------
// GEMM: out = X(M x 1024, fp32) * W(N=1024 x K=1024, fp32)^T + bias(fp32),
// computed in bf16 MFMA (convert-on-load into LDS), bf16 output (workspace).
// layout 0: scatter to [b][h][s][hd]  (m = b*2048+s, n = h*64+hd)
// layout 1: plain row-major [m][n]
// ---------------------------------------------------------------------------
__global__ __launch_bounds__(256) void gemm_bt(
    const float* __restrict__ X,
    const float* __restrict__ W,
    const float* __restrict__ bias,
    unsigned short* __restrict__ out,
    int layout)
{
  constexpr int K = 1024;
  __shared__ unsigned short As[128 * 32];
  __shared__ unsigned short Bs[128 * 32];
  const int tid = threadIdx.x;
  const int mBase = blockIdx.y * 128;
  const int nBase = blockIdx.x * 128;
  const int wave = tid >> 6, lane = tid & 63;
  const int quad = lane >> 4, l16 = lane & 15;
  const int wm = (wave >> 1) << 6, wn = (wave & 1) << 6;

  f32x4 acc[4][4] = {};

  for (int k0 = 0; k0 < K; k0 += 32) {
    float4 xv[2][2], wv[2][2];
#pragma unroll
    for (int i = 0; i < 2; ++i) {
      int e = i * 2048 + tid * 8;
      int row = e >> 5, col = e & 31;
      const float* px = X + (size_t)(mBase + row) * K + (k0 + col);
      const float* pw = W + (size_t)(nBase + row) * K + (k0 + col);
      xv[i][0] = *(const float4*)px;
      xv[i][1] = *(const float4*)(px + 4);
      wv[i][0] = *(const float4*)pw;
      wv[i][1] = *(const float4*)(pw + 4);
    }
#pragma unroll
    for (int i = 0; i < 2; ++i) {
      int e = i * 2048 + tid * 8;
      unsigned short xb[8], wb[8];
#pragma unroll
      for (int t = 0; t < 4; ++t) {
        xb[t]     = f2bf(((const float*)&xv[i][0])[t]);
        xb[t + 4] = f2bf(((const float*)&xv[i][1])[t]);
        wb[t]     = f2bf(((const float*)&wv[i][0])[t]);
        wb[t + 4] = f2bf(((const float*)&wv[i][1])[t]);
      }
      *(uint4*)&As[e] = *(const uint4*)xb;
      *(uint4*)&Bs[e] = *(const uint4*)wb;
    }
    __syncthreads();
    bf16x8 af[4], bff[4];
#pragma unroll
    for (int t = 0; t < 4; ++t) {
      af[t]  = *(const bf16x8*)&As[(wm + t * 16 + l16) * 32 + quad * 8];
      bff[t] = *(const bf16x8*)&Bs[(wn + t * 16 + l16) * 32 + quad * 8];
    }
#pragma unroll
    for (int mt = 0; mt < 4; ++mt)
#pragma unroll
      for (int nt = 0; nt < 4; ++nt)
        acc[mt][nt] = __builtin_amdgcn_mfma_f32_16x16x32_bf16(af[mt], bff[nt], acc[mt][nt], 0, 0, 0);
    __syncthreads();
  }

#pragma unroll
  for (int nt = 0; nt < 4; ++nt) {
    int n = nBase + wn + nt * 16 + l16;
    float bv = bias[n];
#pragma unroll
    for (int mt = 0; mt < 4; ++mt) {
#pragma unroll
      for (int j = 0; j < 4; ++j) {
        int m = mBase + wm + mt * 16 + quad * 4 + j;
        unsigned short o = f2bf(acc[mt][nt][j] + bv);
        if (layout == 0) {
          int b = m >> 11, s = m & 2047;
          int h = n >> 6, hd = n & 63;
          out[(((size_t)(b * 16 + h) * 2048 + s) << 6) + hd] = o;
        } else {
          out[((size_t)m << 10) + n] = o;
        }
      }
    }
  }
}

// ---------------------------------------------------------------------------
// RoPE interleaved, in-place on q and k laid out [bh][s][64] (bf16).
// One thread per (tensor, bh, s, pair): 2*32*2048*32 = 4,194,304 threads.
// ---------------------------------------------------------------------------
__global__ __launch_bounds__(256) void rope_kernel(unsigned short* __restrict__ q,
                                                   unsigned short* __restrict__ k)
{
  int idx = blockIdx.x * 256 + threadIdx.x;
  int tsel = idx >> 21;
  int r = idx & 0x1FFFFF;
  int i = r & 31;
  int srow = r >> 5;          // bh*2048 + s
  int s = srow & 2047;
  unsigned short* p = (tsel ? k : q) + (((size_t)srow) << 6) + (i << 1);
  // inv_freq = 10000^(-i/32) = exp2(-i * log2(10000)/32)
  float inv_freq = exp2f(-(float)i * 0.4152410118609203f);
  float ang = (float)s * inv_freq;
  float sn, cs;
  sincosf(ang, &sn, &cs);
  unsigned int pv = *(const unsigned int*)p;
  float xe = bf2f((unsigned short)(pv & 0xFFFF));
  float xo = bf2f((unsigned short)(pv >> 16));
  float re = xe * cs - xo * sn;
  float ro = xe * sn + xo * cs;
  *(unsigned int*)p = (unsigned int)f2bf(re) | ((unsigned int)f2bf(ro) << 16);
}

// ---------------------------------------------------------------------------
// Flash attention (no mask). Q,K,V laid out [bh][s][64] (bf16).
// Block = 4 waves; each wave owns 32 q-rows (q-tile 128/block).
// KV tile = 64. K staged [kv][72], V transposed [hd][72]. P round-trips
// through LDS (C-layout -> A-layout), barrier-ordered.
// ctx written as [b][s][h*64+hd] (flat [4096][1024], bf16).
// ---------------------------------------------------------------------------
__global__ __launch_bounds__(256) void attn_kernel(
    const unsigned short* __restrict__ Qg,
    const unsigned short* __restrict__ Kg,
    const unsigned short* __restrict__ Vg,
    unsigned short* __restrict__ ctx)
{
  constexpr int S = 2048;
  constexpr int LDW = 72;
  __shared__ unsigned short Ks[64 * LDW];
  __shared__ unsigned short Vt[64 * LDW];
  __shared__ unsigned short Ps[4 * 32 * LDW];

  const int tid = threadIdx.x;
  const int wave = tid >> 6, lane = tid & 63;
  const int quad = lane >> 4, l16 = lane & 15;
  const int bh = blockIdx.x >> 4;
  const int qt = blockIdx.x & 15;
  const int q0 = qt * 128 + wave * 32;

  const unsigned short* Qb = Qg + ((size_t)bh << 17);
  const unsigned short* Kb = Kg + ((size_t)bh << 17);
  const unsigned short* Vb = Vg + ((size_t)bh << 17);

  // Q fragments live in registers for the whole kernel (A-layout).
  bf16x8 qf[2][2];
#pragma unroll
  for (int mt = 0; mt < 2; ++mt)
#pragma unroll
    for (int ks = 0; ks < 2; ++ks)
      qf[mt][ks] = *(const bf16x8*)(Qb + (((size_t)(q0 + mt * 16 + l16)) << 6) + ks * 32 + quad * 8);

  f32x4 oacc[2][4] = {};
  float mrow[8], lrow[8];
#pragma unroll
  for (int r = 0; r < 8; ++r) { mrow[r] = -1e30f; lrow[r] = 0.f; }

  unsigned short* Pw = &Ps[wave * 32 * LDW];
  constexpr float scale = 0.125f;  // 1/sqrt(64)

  for (int kv0 = 0; kv0 < S; kv0 += 64) {
    // --- stage K tile and transposed V tile (all 4 waves cooperate) ---
#pragma unroll
    for (int i = 0; i < 2; ++i) {
      int c = i * 256 + tid;
      int row = c >> 3, col8 = (c & 7) << 3;
      uint4 kd = *(const uint4*)(Kb + (((size_t)(kv0 + row)) << 6) + col8);
      *(uint4*)&Ks[row * LDW + col8] = kd;
      uint4 vd = *(const uint4*)(Vb + (((size_t)(kv0 + row)) << 6) + col8);
      unsigned short ve[8];
      *(uint4*)ve = vd;
#pragma unroll
      for (int t = 0; t < 8; ++t) Vt[(col8 + t) * LDW + row] = ve[t];
    }
    __syncthreads();

    // --- S = Q K^T ---
    bf16x8 kf[4][2];
#pragma unroll
    for (int nt = 0; nt < 4; ++nt)
#pragma unroll
      for (int ks = 0; ks < 2; ++ks)
        kf[nt][ks] = *(const bf16x8*)&Ks[(nt * 16 + l16) * LDW + ks * 32 + quad * 8];
    f32x4 sacc[2][4] = {};
#pragma unroll
    for (int mt = 0; mt < 2; ++mt)
#pragma unroll
      for (int nt = 0; nt < 4; ++nt)
#pragma unroll
        for (int ks = 0; ks < 2; ++ks)
          sacc[mt][nt] = __builtin_amdgcn_mfma_f32_16x16x32_bf16(qf[mt][ks], kf[nt][ks], sacc[mt][nt], 0, 0, 0);

    // --- online softmax (rows live across the 16-lane quad-group) ---
#pragma unroll
    for (int mt = 0; mt < 2; ++mt) {
#pragma unroll
      for (int j = 0; j < 4; ++j) {
        int r = mt * 4 + j;
        float tmax = fmaxf(fmaxf(sacc[mt][0][j], sacc[mt][1][j]),
                           fmaxf(sacc[mt][2][j], sacc[mt][3][j])) * scale;
#pragma unroll
        for (int off = 1; off < 16; off <<= 1)
          tmax = fmaxf(tmax, __shfl_xor(tmax, off));
        float mnew = fmaxf(mrow[r], tmax);
        float alpha = __expf(mrow[r] - mnew);
        float rsum = 0.f;
#pragma unroll
        for (int nt = 0; nt < 4; ++nt) {
          float p = __expf(sacc[mt][nt][j] * scale - mnew);
          sacc[mt][nt][j] = p;
          rsum += p;
        }
#pragma unroll
        for (int off = 1; off < 16; off <<= 1)
          rsum += __shfl_xor(rsum, off);
        lrow[r] = lrow[r] * alpha + rsum;
        mrow[r] = mnew;
#pragma unroll
        for (int nt = 0; nt < 4; ++nt)
          oacc[mt][nt][j] *= alpha;
      }
    }

    // --- P: C-layout regs -> LDS -> A-layout frags (barrier-ordered) ---
#pragma unroll
    for (int mt = 0; mt < 2; ++mt)
#pragma unroll
      for (int nt = 0; nt < 4; ++nt)
#pragma unroll
        for (int j = 0; j < 4; ++j)
          Pw[(mt * 16 + quad * 4 + j) * LDW + nt * 16 + l16] = f2bf(sacc[mt][nt][j]);
    __syncthreads();

    // --- O += P V ---
#pragma unroll
    for (int mt = 0; mt < 2; ++mt) {
#pragma unroll
      for (int ks = 0; ks < 2; ++ks) {
        bf16x8 pf = *(const bf16x8*)&Pw[(mt * 16 + l16) * LDW + ks * 32 + quad * 8];
#pragma unroll
        for (int nt = 0; nt < 4; ++nt) {
          bf16x8 vf = *(const bf16x8*)&Vt[(nt * 16 + l16) * LDW + ks * 32 + quad * 8];
          oacc[mt][nt] = __builtin_amdgcn_mfma_f32_16x16x32_bf16(pf, vf, oacc[mt][nt], 0, 0, 0);
        }
      }
    }
    __syncthreads();
  }

  // --- epilogue: O /= l, write ctx [b][s][h*64+hd] ---
  float rinv[8];
#pragma unroll
  for (int r = 0; r < 8; ++r) rinv[r] = 1.0f / lrow[r];
  const int b = bh >> 4, h = bh & 15;
#pragma unroll
  for (int mt = 0; mt < 2; ++mt)
#pragma unroll
    for (int nt = 0; nt < 4; ++nt)
#pragma unroll
      for (int j = 0; j < 4; ++j) {
        int s = q0 + mt * 16 + quad * 4 + j;
        int d = h * 64 + nt * 16 + l16;
        ctx[((size_t)(b * 2048 + s) << 10) + d] = f2bf(oacc[mt][nt][j] * rinv[mt * 4 + j]);
      }
}

// ---------------------------------------------------------------------------
// Final GEMM: X is bf16 (ctx workspace), W/bias fp32, OUTPUT fp32 (d_out).
// ---------------------------------------------------------------------------
__global__ __launch_bounds__(256) void gemm_bt_out(
    const unsigned short* __restrict__ X,
    const float* __restrict__ W,
    const float* __restrict__ bias,
    float* __restrict__ out)
{
  constexpr int K = 1024;
  __shared__ unsigned short As[128 * 32];
  __shared__ unsigned short Bs[128 * 32];
  const int tid = threadIdx.x;
  const int mBase = blockIdx.y * 128;
  const int nBase = blockIdx.x * 128;
  const int wave = tid >> 6, lane = tid & 63;
  const int quad = lane >> 4, l16 = lane & 15;
  const int wm = (wave >> 1) << 6, wn = (wave & 1) << 6;

  f32x4 acc[4][4] = {};

  for (int k0 = 0; k0 < K; k0 += 32) {
    uint4 xv[2];
    float4 wv[2][2];
#pragma unroll
    for (int i = 0; i < 2; ++i) {
      int e = i * 2048 + tid * 8;
      int row = e >> 5, col = e & 31;
      xv[i] = *(const uint4*)(X + (size_t)(mBase + row) * K + (k0 + col));
      const float* pw = W + (size_t)(nBase + row) * K + (k0 + col);
      wv[i][0] = *(const float4*)pw;
      wv[i][1] = *(const float4*)(pw + 4);
    }
#pragma unroll
    for (int i = 0; i < 2; ++i) {
      int e = i * 2048 + tid * 8;
      unsigned short wb[8];
#pragma unroll
      for (int t = 0; t < 4; ++t) {
        wb[t]     = f2bf(((const float*)&wv[i][0])[t]);
        wb[t + 4] = f2bf(((const float*)&wv[i][1])[t]);
      }
      *(uint4*)&As[e] = xv[i];
      *(uint4*)&Bs[e] = *(const uint4*)wb;
    }
    __syncthreads();
    bf16x8 af[4], bff[4];
#pragma unroll
    for (int t = 0; t < 4; ++t) {
      af[t]  = *(const bf16x8*)&As[(wm + t * 16 + l16) * 32 + quad * 8];
      bff[t] = *(const bf16x8*)&Bs[(wn + t * 16 + l16) * 32 + quad * 8];
    }
#pragma unroll
    for (int mt = 0; mt < 4; ++mt)
#pragma unroll
      for (int nt = 0; nt < 4; ++nt)
        acc[mt][nt] = __builtin_amdgcn_mfma_f32_16x16x32_bf16(af[mt], bff[nt], acc[mt][nt], 0, 0, 0);
    __syncthreads();
  }

#pragma unroll
  for (int nt = 0; nt < 4; ++nt) {
    int n = nBase + wn + nt * 16 + l16;
    float bv = bias[n];
#pragma unroll
    for (int mt = 0; mt < 4; ++mt) {
#pragma unroll
      for (int j = 0; j < 4; ++j) {
        int m = mBase + wm + mt * 16 + quad * 4 + j;
        out[((size_t)m << 10) + n] = acc[mt][nt][j] + bv;
      }
    }
  }
}

// ---------------------------------------------------------------------------
extern "C" void kernel_launch(void* const* d_in, const int* in_sizes, int n_in,
                              void* d_out, int out_size, void* d_ws, size_t ws_size,
                              hipStream_t stream) {
  const float* x_q  = (const float*)d_in[0];
  const float* x_kv = (const float*)d_in[1];
  const float* wq   = (const float*)d_in[2];
  const float* bq   = (const float*)d_in[3];
  const float* wk   = (const float*)d_in[4];
  const float* bk   = (const float*)d_in[5];
  const float* wv   = (const float*)d_in[6];
  const float* bv   = (const float*)d_in[7];
  const float* wo   = (const float*)d_in[8];
  const float* bo   = (const float*)d_in[9];

  unsigned short* q   = (unsigned short*)d_ws;        // [bh][s][64] bf16
  unsigned short* k   = q + 4194304;                  // [bh][s][64] bf16
  unsigned short* v   = k + 4194304;                  // [bh][s][64] bf16
  unsigned short* ctx = v + 4194304;                  // [b*s][1024] bf16
  float* out = (float*)d_out;                         // fp32, per reference

  dim3 gproj(8, 32);  // n-tiles x m-tiles
  gemm_bt<<<gproj, 256, 0, stream>>>(x_q,  wq, bq, q, 0);
  gemm_bt<<<gproj, 256, 0, stream>>>(x_kv, wk, bk, k, 0);
  gemm_bt<<<gproj, 256, 0, stream>>>(x_kv, wv, bv, v, 0);
  rope_kernel<<<16384, 256, 0, stream>>>(q, k);
  attn_kernel<<<512, 256, 0, stream>>>(q, k, v, ctx);
  gemm_bt_out<<<gproj, 256, 0, stream>>>(ctx, wo, bo, out);
}

// Round 5
// 320.981 us; speedup vs baseline: 1.2711x; 1.2711x over previous
//
#include <hip/hip_runtime.h>
#include <cstdint>

typedef __attribute__((ext_vector_type(8))) short bf16x8;
typedef __attribute__((ext_vector_type(4))) float f32x4;

#define DEV static __device__ __forceinline__

DEV unsigned short f2bf(float f) {
  unsigned int u = __builtin_bit_cast(unsigned int, f);
  u += 0x7FFFu + ((u >> 16) & 1u);
  return (unsigned short)(u >> 16);
}
DEV void async_copy16(const unsigned short* g, unsigned short* l) {
  __builtin_amdgcn_global_load_lds(
      (const __attribute__((address_space(1))) unsigned int*)(uintptr_t)g,
      (__attribute__((address_space(3))) unsigned int*)(uintptr_t)l,
      16, 0, 0);
}

// ---------------------------------------------------------------------------
// Convert the 4 weight matrices (each 1024x1024 fp32) to bf16 workspace.
// 2^20 threads, one float4 -> 4 bf16 each.
// ---------------------------------------------------------------------------
__global__ __launch_bounds__(256) void cvt_w4(
    const float* __restrict__ w0, const float* __restrict__ w1,
    const float* __restrict__ w2, const float* __restrict__ w3,
    unsigned short* __restrict__ out)
{
  int t = blockIdx.x * 256 + threadIdx.x;   // 0 .. 2^20-1
  int m = t >> 18;
  int off = (t & 0x3FFFF) << 2;
  const float* src = m == 0 ? w0 : m == 1 ? w1 : m == 2 ? w2 : w3;
  float4 v = *(const float4*)(src + off);
  unsigned short pk[4] = { f2bf(v.x), f2bf(v.y), f2bf(v.z), f2bf(v.w) };
  *(uint2*)(out + (((size_t)m) << 20) + off) = *(const uint2*)pk;
}

// ---------------------------------------------------------------------------
// Fused QKV projection: z = blockIdx.z selects {Q, K, V}.
// out = X(fp32) * W^T + bias, bf16 MFMA. A-side fp32 cvt-staged; B-side
// bf16 via global_load_lds when WBF (pre-converted weights), else fp32 cvt.
// z<2 -> scatter [bh][s][64]; z==2 -> V^T [bh][hd][s] (b64 packed).
// ---------------------------------------------------------------------------
template <bool WBF>
__global__ __launch_bounds__(256) void gemm_qkv(
    const float* __restrict__ xq, const float* __restrict__ xkv,
    const void* __restrict__ Wq, const void* __restrict__ Wk,
    const void* __restrict__ Wv,
    const float* __restrict__ bq, const float* __restrict__ bk,
    const float* __restrict__ bv,
    unsigned short* __restrict__ outq, unsigned short* __restrict__ outk,
    unsigned short* __restrict__ outvT)
{
  constexpr int K = 1024;
  __shared__ unsigned short As[128 * 32];
  __shared__ unsigned short Bs[128 * 32];
  const int z = blockIdx.z;
  const float* X = (z == 0) ? xq : xkv;
  const void* Wp = (z == 0) ? Wq : (z == 1) ? Wk : Wv;
  const float* bias = (z == 0) ? bq : (z == 1) ? bk : bv;

  const int tid = threadIdx.x;
  const int mBase = blockIdx.y * 128, nBase = blockIdx.x * 128;
  const int wave = tid >> 6, lane = tid & 63;
  const int quad = lane >> 4, l16 = lane & 15;
  const int wm = (wave >> 1) << 6, wn = (wave & 1) << 6;

  f32x4 acc[4][4] = {};

  for (int k0 = 0; k0 < K; k0 += 32) {
    if constexpr (WBF) {
      const unsigned short* Wb = (const unsigned short*)Wp;
#pragma unroll
      for (int i = 0; i < 2; ++i) {
        int e = i * 2048 + tid * 8;
        int row = e >> 5, col = e & 31;
        async_copy16(Wb + (size_t)(nBase + row) * K + (k0 + col), &Bs[e]);
      }
    }
    float4 xv[2][2], wv[2][2];
#pragma unroll
    for (int i = 0; i < 2; ++i) {
      int e = i * 2048 + tid * 8;
      int row = e >> 5, col = e & 31;
      const float* px = X + (size_t)(mBase + row) * K + (k0 + col);
      xv[i][0] = *(const float4*)px;
      xv[i][1] = *(const float4*)(px + 4);
      if constexpr (!WBF) {
        const float* pw = (const float*)Wp + (size_t)(nBase + row) * K + (k0 + col);
        wv[i][0] = *(const float4*)pw;
        wv[i][1] = *(const float4*)(pw + 4);
      }
    }
#pragma unroll
    for (int i = 0; i < 2; ++i) {
      int e = i * 2048 + tid * 8;
      unsigned short xb[8];
#pragma unroll
      for (int t = 0; t < 4; ++t) {
        xb[t]     = f2bf(((const float*)&xv[i][0])[t]);
        xb[t + 4] = f2bf(((const float*)&xv[i][1])[t]);
      }
      *(uint4*)&As[e] = *(const uint4*)xb;
      if constexpr (!WBF) {
        unsigned short wb[8];
#pragma unroll
        for (int t = 0; t < 4; ++t) {
          wb[t]     = f2bf(((const float*)&wv[i][0])[t]);
          wb[t + 4] = f2bf(((const float*)&wv[i][1])[t]);
        }
        *(uint4*)&Bs[e] = *(const uint4*)wb;
      }
    }
    __syncthreads();
    bf16x8 af[4], bff[4];
#pragma unroll
    for (int t = 0; t < 4; ++t) {
      af[t]  = *(const bf16x8*)&As[(wm + t * 16 + l16) * 32 + quad * 8];
      bff[t] = *(const bf16x8*)&Bs[(wn + t * 16 + l16) * 32 + quad * 8];
    }
#pragma unroll
    for (int mt = 0; mt < 4; ++mt)
#pragma unroll
      for (int nt = 0; nt < 4; ++nt)
        acc[mt][nt] = __builtin_amdgcn_mfma_f32_16x16x32_bf16(af[mt], bff[nt], acc[mt][nt], 0, 0, 0);
    __syncthreads();
  }

  if (z < 2) {
    unsigned short* out = z ? outk : outq;
#pragma unroll
    for (int nt = 0; nt < 4; ++nt) {
      int n = nBase + wn + nt * 16 + l16;
      float bv2 = bias[n];
      int h = n >> 6, hd = n & 63;
#pragma unroll
      for (int mt = 0; mt < 4; ++mt) {
#pragma unroll
        for (int j = 0; j < 4; ++j) {
          int m = mBase + wm + mt * 16 + quad * 4 + j;
          int b = m >> 11, s = m & 2047;
          out[(((size_t)(b * 16 + h) * 2048 + s) << 6) + hd] = f2bf(acc[mt][nt][j] + bv2);
        }
      }
    }
  } else {
#pragma unroll
    for (int nt = 0; nt < 4; ++nt) {
      int n = nBase + wn + nt * 16 + l16;
      float bv2 = bias[n];
      int h = n >> 6, hd = n & 63;
#pragma unroll
      for (int mt = 0; mt < 4; ++mt) {
        int m0 = mBase + wm + mt * 16 + quad * 4;
        int b = m0 >> 11, s = m0 & 2047;
        unsigned short pk[4];
#pragma unroll
        for (int j = 0; j < 4; ++j) pk[j] = f2bf(acc[mt][nt][j] + bv2);
        *(uint2*)&outvT[(((size_t)(b * 16 + h) * 64 + hd) << 11) + s] = *(const uint2*)pk;
      }
    }
  }
}

// ---------------------------------------------------------------------------
// RoPE interleaved, in-place on q and k laid out [bh][s][64] (bf16).
// ---------------------------------------------------------------------------
__global__ __launch_bounds__(256) void rope_kernel(unsigned short* __restrict__ q,
                                                   unsigned short* __restrict__ k)
{
  int idx = blockIdx.x * 256 + threadIdx.x;
  int tsel = idx >> 21;
  int r = idx & 0x1FFFFF;
  int i = r & 31;
  int srow = r >> 5;          // bh*2048 + s
  int s = srow & 2047;
  unsigned short* p = (tsel ? k : q) + (((size_t)srow) << 6) + (i << 1);
  float inv_freq = exp2f(-(float)i * 0.4152410118609203f);
  float ang = (float)s * inv_freq;
  float sn, cs;
  sincosf(ang, &sn, &cs);
  unsigned int pv = *(const unsigned int*)p;
  float xe = __builtin_bit_cast(float, (pv & 0xFFFFu) << 16);
  float xo = __builtin_bit_cast(float, pv & 0xFFFF0000u);
  float re = xe * cs - xo * sn;
  float ro = xe * sn + xo * cs;
  *(unsigned int*)p = (unsigned int)f2bf(re) | ((unsigned int)f2bf(ro) << 16);
}

// ---------------------------------------------------------------------------
// Flash attention v2 (S^T formulation, barrier-free).
// Q,K: [bh][s][64]; VT: [bh][hd][s]; ctx: [b*2048+s][1024] (bf16).
// 4 independent waves/block; wave owns 32 q-rows; KV tile 64.
// S^T = K·Q^T  (a=K rows, b=Q rows, both direct global 16B loads).
// Softmax per q = in-lane over 16 kv + 2 shuffles (quads).
// P stored q-major in per-wave LDS (b64 writes, b128 reads, 2-way=free).
// O^T = V^T·P^T (a=V^T rows direct global, b=P natural rows from LDS).
// ---------------------------------------------------------------------------
__global__ __launch_bounds__(256) void attn_v2(
    const unsigned short* __restrict__ Qg,
    const unsigned short* __restrict__ Kg,
    const unsigned short* __restrict__ VT,
    unsigned short* __restrict__ ctx)
{
  constexpr int LDP = 72;
  __shared__ unsigned short Ps[4 * 32 * LDP];
  const int tid = threadIdx.x, wave = tid >> 6, lane = tid & 63;
  const int quad = lane >> 4, l16 = lane & 15;
  const int bh = blockIdx.x & 31;        // XCD-swizzle: all q-tiles of a head on one XCD
  const int qt = blockIdx.x >> 5;
  const int q0 = qt * 128 + wave * 32;
  const unsigned short* Qb = Qg + ((size_t)bh << 17);
  const unsigned short* Kb = Kg + ((size_t)bh << 17);
  const unsigned short* Vb = VT + ((size_t)bh << 17);
  unsigned short* Pw = &Ps[wave * 32 * LDP];
  constexpr float scale = 0.125f;        // 1/sqrt(64)

  // Q b-frags, register-resident: [n=q][k=d]
  bf16x8 qf[2][2];
#pragma unroll
  for (int mq = 0; mq < 2; ++mq)
#pragma unroll
    for (int kd = 0; kd < 2; ++kd)
      qf[mq][kd] = *(const bf16x8*)(Qb + (size_t)(q0 + mq * 16 + l16) * 64 + kd * 32 + quad * 8);

  f32x4 oacc[4][2] = {};                 // O^T tiles [th(hd)][mq(q)]
  float mrow[2] = { -1e30f, -1e30f }, lrow[2] = { 0.f, 0.f };

  for (int kv0 = 0; kv0 < 2048; kv0 += 64) {
    // --- S^T = K·Q^T : st[tk][mq], C-layout [kv=quad*4+jr][q=l16] ---
    f32x4 st[4][2] = {};
#pragma unroll
    for (int tk = 0; tk < 4; ++tk) {
#pragma unroll
      for (int kd = 0; kd < 2; ++kd) {
        bf16x8 kf = *(const bf16x8*)(Kb + (size_t)(kv0 + tk * 16 + l16) * 64 + kd * 32 + quad * 8);
#pragma unroll
        for (int mq = 0; mq < 2; ++mq)
          st[tk][mq] = __builtin_amdgcn_mfma_f32_16x16x32_bf16(kf, qf[mq][kd], st[tk][mq], 0, 0, 0);
      }
    }

    // --- online softmax per q column ---
#pragma unroll
    for (int mq = 0; mq < 2; ++mq) {
      float tmax = st[0][mq][0];
#pragma unroll
      for (int tk = 0; tk < 4; ++tk)
#pragma unroll
        for (int jr = 0; jr < 4; ++jr)
          tmax = fmaxf(tmax, st[tk][mq][jr]);
      tmax *= scale;
      tmax = fmaxf(tmax, __shfl_xor(tmax, 16));
      tmax = fmaxf(tmax, __shfl_xor(tmax, 32));
      float mnew = fmaxf(mrow[mq], tmax);
      float alpha = __expf(mrow[mq] - mnew);
      float rsum = 0.f;
#pragma unroll
      for (int tk = 0; tk < 4; ++tk)
#pragma unroll
        for (int jr = 0; jr < 4; ++jr) {
          float p = __expf(st[tk][mq][jr] * scale - mnew);
          st[tk][mq][jr] = p;
          rsum += p;
        }
      rsum += __shfl_xor(rsum, 16);
      rsum += __shfl_xor(rsum, 32);
      lrow[mq] = lrow[mq] * alpha + rsum;
      mrow[mq] = mnew;
#pragma unroll
      for (int th = 0; th < 4; ++th)
        oacc[th][mq] *= alpha;
    }

    // --- store P^T values as q-major P rows (b64 packed, conflict-free) ---
#pragma unroll
    for (int mq = 0; mq < 2; ++mq)
#pragma unroll
      for (int tk = 0; tk < 4; ++tk) {
        unsigned short pk[4];
#pragma unroll
        for (int jr = 0; jr < 4; ++jr) pk[jr] = f2bf(st[tk][mq][jr]);
        *(uint2*)&Pw[(mq * 16 + l16) * LDP + tk * 16 + quad * 4] = *(const uint2*)pk;
      }

    // --- O^T += V^T·P^T : a=V^T rows (global), b=P rows (LDS b128) ---
#pragma unroll
    for (int ks = 0; ks < 2; ++ks) {
      bf16x8 pf[2];
#pragma unroll
      for (int mq = 0; mq < 2; ++mq)
        pf[mq] = *(const bf16x8*)&Pw[(mq * 16 + l16) * LDP + ks * 32 + quad * 8];
#pragma unroll
      for (int th = 0; th < 4; ++th) {
        bf16x8 vf = *(const bf16x8*)(Vb + (size_t)(th * 16 + l16) * 2048 + kv0 + ks * 32 + quad * 8);
#pragma unroll
        for (int mq = 0; mq < 2; ++mq)
          oacc[th][mq] = __builtin_amdgcn_mfma_f32_16x16x32_bf16(vf, pf[mq], oacc[th][mq], 0, 0, 0);
      }
    }
  }

  // --- epilogue: O^T/l -> ctx[b][s][h*64+hd], b64 packed ---
  const int b = bh >> 4, h = bh & 15;
  float rinv[2] = { 1.0f / lrow[0], 1.0f / lrow[1] };
#pragma unroll
  for (int mq = 0; mq < 2; ++mq) {
    int s = q0 + mq * 16 + l16;
#pragma unroll
    for (int th = 0; th < 4; ++th) {
      unsigned short pk[4];
#pragma unroll
      for (int jr = 0; jr < 4; ++jr) pk[jr] = f2bf(oacc[th][mq][jr] * rinv[mq]);
      *(uint2*)&ctx[((size_t)(b * 2048 + s) << 10) + h * 64 + th * 16 + quad * 4] = *(const uint2*)pk;
    }
  }
}

// ---------------------------------------------------------------------------
// O-projection, primary path: both operands bf16, full async staging.
// 64x128 tile, grid (8,64) = 512 blocks (2/CU). Output fp32 (d_out).
// ---------------------------------------------------------------------------
__global__ __launch_bounds__(256) void gemm_o_bf(
    const unsigned short* __restrict__ X,   // ctx bf16 [4096][1024]
    const unsigned short* __restrict__ Wb,  // wo bf16 [1024][1024]
    const float* __restrict__ bias,
    float* __restrict__ out)
{
  constexpr int K = 1024;
  __shared__ unsigned short As[64 * 32];
  __shared__ unsigned short Bs[128 * 32];
  const int tid = threadIdx.x;
  const int mBase = blockIdx.y * 64, nBase = blockIdx.x * 128;
  const int wave = tid >> 6, lane = tid & 63;
  const int quad = lane >> 4, l16 = lane & 15;
  const int wm = (wave >> 1) * 32, wn = (wave & 1) * 64;

  f32x4 acc[2][4] = {};

  for (int k0 = 0; k0 < K; k0 += 32) {
    {
      int e = tid * 8;
      int row = e >> 5, col = e & 31;
      async_copy16(X + (size_t)(mBase + row) * K + (k0 + col), &As[e]);
    }
#pragma unroll
    for (int i = 0; i < 2; ++i) {
      int e = i * 2048 + tid * 8;
      int row = e >> 5, col = e & 31;
      async_copy16(Wb + (size_t)(nBase + row) * K + (k0 + col), &Bs[e]);
    }
    __syncthreads();
    bf16x8 af[2], bff[4];
#pragma unroll
    for (int t = 0; t < 2; ++t)
      af[t] = *(const bf16x8*)&As[(wm + t * 16 + l16) * 32 + quad * 8];
#pragma unroll
    for (int t = 0; t < 4; ++t)
      bff[t] = *(const bf16x8*)&Bs[(wn + t * 16 + l16) * 32 + quad * 8];
#pragma unroll
    for (int mt = 0; mt < 2; ++mt)
#pragma unroll
      for (int nt = 0; nt < 4; ++nt)
        acc[mt][nt] = __builtin_amdgcn_mfma_f32_16x16x32_bf16(af[mt], bff[nt], acc[mt][nt], 0, 0, 0);
    __syncthreads();
  }

#pragma unroll
  for (int nt = 0; nt < 4; ++nt) {
    int n = nBase + wn + nt * 16 + l16;
    float bv = bias[n];
#pragma unroll
    for (int mt = 0; mt < 2; ++mt)
#pragma unroll
      for (int j = 0; j < 4; ++j) {
        int m = mBase + wm + mt * 16 + quad * 4 + j;
        out[((size_t)m << 10) + n] = acc[mt][nt][j] + bv;
      }
  }
}

// ---------------------------------------------------------------------------
// O-projection, fallback: X bf16, W/bias fp32 cvt-staged (round-4 proven).
// ---------------------------------------------------------------------------
__global__ __launch_bounds__(256) void gemm_bt_out(
    const unsigned short* __restrict__ X,
    const float* __restrict__ W,
    const float* __restrict__ bias,
    float* __restrict__ out)
{
  constexpr int K = 1024;
  __shared__ unsigned short As[128 * 32];
  __shared__ unsigned short Bs[128 * 32];
  const int tid = threadIdx.x;
  const int mBase = blockIdx.y * 128;
  const int nBase = blockIdx.x * 128;
  const int wave = tid >> 6, lane = tid & 63;
  const int quad = lane >> 4, l16 = lane & 15;
  const int wm = (wave >> 1) << 6, wn = (wave & 1) << 6;

  f32x4 acc[4][4] = {};

  for (int k0 = 0; k0 < K; k0 += 32) {
    uint4 xv[2];
    float4 wv[2][2];
#pragma unroll
    for (int i = 0; i < 2; ++i) {
      int e = i * 2048 + tid * 8;
      int row = e >> 5, col = e & 31;
      xv[i] = *(const uint4*)(X + (size_t)(mBase + row) * K + (k0 + col));
      const float* pw = W + (size_t)(nBase + row) * K + (k0 + col);
      wv[i][0] = *(const float4*)pw;
      wv[i][1] = *(const float4*)(pw + 4);
    }
#pragma unroll
    for (int i = 0; i < 2; ++i) {
      int e = i * 2048 + tid * 8;
      unsigned short wb[8];
#pragma unroll
      for (int t = 0; t < 4; ++t) {
        wb[t]     = f2bf(((const float*)&wv[i][0])[t]);
        wb[t + 4] = f2bf(((const float*)&wv[i][1])[t]);
      }
      *(uint4*)&As[e] = xv[i];
      *(uint4*)&Bs[e] = *(const uint4*)wb;
    }
    __syncthreads();
    bf16x8 af[4], bff[4];
#pragma unroll
    for (int t = 0; t < 4; ++t) {
      af[t]  = *(const bf16x8*)&As[(wm + t * 16 + l16) * 32 + quad * 8];
      bff[t] = *(const bf16x8*)&Bs[(wn + t * 16 + l16) * 32 + quad * 8];
    }
#pragma unroll
    for (int mt = 0; mt < 4; ++mt)
#pragma unroll
      for (int nt = 0; nt < 4; ++nt)
        acc[mt][nt] = __builtin_amdgcn_mfma_f32_16x16x32_bf16(af[mt], bff[nt], acc[mt][nt], 0, 0, 0);
    __syncthreads();
  }

#pragma unroll
  for (int nt = 0; nt < 4; ++nt) {
    int n = nBase + wn + nt * 16 + l16;
    float bv = bias[n];
#pragma unroll
    for (int mt = 0; mt < 4; ++mt) {
#pragma unroll
      for (int j = 0; j < 4; ++j) {
        int m = mBase + wm + mt * 16 + quad * 4 + j;
        out[((size_t)m << 10) + n] = acc[mt][nt][j] + bv;
      }
    }
  }
}

// ---------------------------------------------------------------------------
extern "C" void kernel_launch(void* const* d_in, const int* in_sizes, int n_in,
                              void* d_out, int out_size, void* d_ws, size_t ws_size,
                              hipStream_t stream) {
  const float* x_q  = (const float*)d_in[0];
  const float* x_kv = (const float*)d_in[1];
  const float* wq   = (const float*)d_in[2];
  const float* bq   = (const float*)d_in[3];
  const float* wk   = (const float*)d_in[4];
  const float* bk   = (const float*)d_in[5];
  const float* wv   = (const float*)d_in[6];
  const float* bv   = (const float*)d_in[7];
  const float* wo   = (const float*)d_in[8];
  const float* bo   = (const float*)d_in[9];

  const bool big = ws_size >= 41943040;   // bf16-weights path needs 40 MiB
  unsigned short* base = (unsigned short*)d_ws;
  unsigned short *q, *k, *vT, *ctx, *wqb = 0, *wkb = 0, *wvb = 0, *wob = 0;
  if (big) {
    wqb = base;
    wkb = base + (1u << 20);
    wvb = base + (2u << 20);
    wob = base + (3u << 20);
    q   = base + (4u << 20);
  } else {
    q = base;
  }
  k   = q + 4194304;
  vT  = k + 4194304;
  ctx = vT + 4194304;
  float* out = (float*)d_out;

  dim3 gqkv(8, 32, 3);
  if (big) {
    cvt_w4<<<4096, 256, 0, stream>>>(wq, wk, wv, wo, base);
    gemm_qkv<true><<<gqkv, 256, 0, stream>>>(x_q, x_kv, wqb, wkb, wvb,
                                             bq, bk, bv, q, k, vT);
  } else {
    gemm_qkv<false><<<gqkv, 256, 0, stream>>>(x_q, x_kv, wq, wk, wv,
                                              bq, bk, bv, q, k, vT);
  }
  rope_kernel<<<16384, 256, 0, stream>>>(q, k);
  attn_v2<<<512, 256, 0, stream>>>(q, k, vT, ctx);
  if (big)
    gemm_o_bf<<<dim3(8, 64), 256, 0, stream>>>(ctx, wob, bo, out);
  else
    gemm_bt_out<<<dim3(8, 32), 256, 0, stream>>>(ctx, wo, bo, out);
}